// Round 12
// baseline (268.172 us; speedup 1.0000x reference)
//
#include <hip/hip_runtime.h>
#include <stdint.h>

typedef unsigned short u16;
typedef __attribute__((ext_vector_type(8))) unsigned short ushort8;
typedef __attribute__((ext_vector_type(4))) unsigned short ushort4v;
typedef __attribute__((ext_vector_type(8))) __bf16 bf16x8;
typedef __attribute__((ext_vector_type(4))) float f32x4;

__device__ __forceinline__ u16 f2bf(float f) {
    union { float f; unsigned int u; } v; v.f = f;
    unsigned int r = v.u + 0x7FFFu + ((v.u >> 16) & 1u);   // RNE
    return (u16)(r >> 16);
}
__device__ __forceinline__ float bf2f(u16 b) {
    union { unsigned int u; float f; } v; v.u = ((unsigned int)b) << 16;
    return v.f;
}

typedef __attribute__((address_space(1))) const uint32_t* gptr_t;
typedef __attribute__((address_space(3))) uint32_t* lptr_t;
__device__ __forceinline__ void async_copy16(const void* g, void* l) {
    __builtin_amdgcn_global_load_lds((gptr_t)g, (lptr_t)l, 16, 0, 0);
}

// ---------------- merged pre-pass: x->bf16, sign(W1)->bf16, W4 -> W4T ----------------

__global__ __launch_bounds__(256) void pre_kernel(
    const float* __restrict__ x, const float* __restrict__ W1,
    const float* __restrict__ W4,
    u16* __restrict__ Xb, u16* __restrict__ W1b, u16* __restrict__ W4T)
{
    const int b = blockIdx.x;
    if (b < 12288) {
        int i = b * 256 + threadIdx.x;
        const float4* p = (const float4*)(x + (size_t)i * 8);
        float4 x0 = p[0], x1 = p[1];
        ushort8 o;
        o[0] = f2bf(x0.x); o[1] = f2bf(x0.y); o[2] = f2bf(x0.z); o[3] = f2bf(x0.w);
        o[4] = f2bf(x1.x); o[5] = f2bf(x1.y); o[6] = f2bf(x1.z); o[7] = f2bf(x1.w);
        *(ushort8*)(Xb + (size_t)i * 8) = o;
    } else if (b < 13824) {
        int i = (b - 12288) * 256 + threadIdx.x;
        const float4* p = (const float4*)(W1 + (size_t)i * 8);
        float4 x0 = p[0], x1 = p[1];
        ushort8 o;
        o[0] = x0.x >= 0.f ? 0x3F80 : 0xBF80;
        o[1] = x0.y >= 0.f ? 0x3F80 : 0xBF80;
        o[2] = x0.z >= 0.f ? 0x3F80 : 0xBF80;
        o[3] = x0.w >= 0.f ? 0x3F80 : 0xBF80;
        o[4] = x1.x >= 0.f ? 0x3F80 : 0xBF80;
        o[5] = x1.y >= 0.f ? 0x3F80 : 0xBF80;
        o[6] = x1.z >= 0.f ? 0x3F80 : 0xBF80;
        o[7] = x1.w >= 0.f ? 0x3F80 : 0xBF80;
        *(ushort8*)(W1b + (size_t)i * 8) = o;
    } else {
        int idx = (b - 13824) * 256 + threadIdx.x;
        int k = idx >> 4, c = idx & 15;
        u16 v = 0;
        if (c < 10) v = (W4[(size_t)c * 1024 + k] >= 0.f) ? 0x3F80 : 0xBF80;
        W4T[idx] = v;
    }
}

// W' = bf16(sign(W)*sc_k), bias_n = sum_k sign(W)*sh_k.  W [1024][1024] f32.
__global__ __launch_bounds__(256) void rescale_w(
    const float* __restrict__ W, const float* __restrict__ ss,
    u16* __restrict__ Wp, float* __restrict__ bias)
{
    const int lane = threadIdx.x & 63;
    const int wid  = threadIdx.x >> 6;
    const int r    = blockIdx.x * 4 + wid;
    float bsum = 0.f;
    #pragma unroll
    for (int k0 = 0; k0 < 1024; k0 += 256) {
        int k = k0 + lane * 4;
        float4 w  = *(const float4*)(W + (size_t)r * 1024 + k);
        float4 sc = *(const float4*)(ss + k);
        float4 sh = *(const float4*)(ss + 1024 + k);
        ushort4v o;
        o[0] = f2bf(w.x >= 0.f ? sc.x : -sc.x);
        o[1] = f2bf(w.y >= 0.f ? sc.y : -sc.y);
        o[2] = f2bf(w.z >= 0.f ? sc.z : -sc.z);
        o[3] = f2bf(w.w >= 0.f ? sc.w : -sc.w);
        bsum += (w.x >= 0.f ? sh.x : -sh.x) + (w.y >= 0.f ? sh.y : -sh.y)
              + (w.z >= 0.f ? sh.z : -sh.z) + (w.w >= 0.f ? sh.w : -sh.w);
        *(ushort4v*)(Wp + (size_t)r * 1024 + k) = o;
    }
    #pragma unroll
    for (int off = 32; off; off >>= 1) bsum += __shfl_xor(bsum, off, 64);
    if (lane == 0) bias[r] = bsum;
}

// XCD-aware bijective swizzle for grid (64,8)
__device__ __forceinline__ void xcd_map(int& mm, int& jj) {
    const int d = blockIdx.x + blockIdx.y * gridDim.x;
    mm = (d & 7) + (d >> 6) * 8;
    jj = (d >> 3) & 7;
}

// ---------------- GEMM (bf16, 16x16x32 MFMA, single-barrier overlapped pipeline) ----------------
// H = bf16(relu(A @ B^T [+ bias])), fused BN column stats.
// 128x128 tile, BK=64, 4 waves (64x64), dbuf LDS via global_load_lds
// (linear dest, pre-swizzled global source), XOR-swizzled reads.
// Per iter t: vmcnt(0) [own t+1 loads; exactly counted] -> barrier [cross-wave:
// t+1 landed, buf(t) reads done] -> STAGE(t+2)->buf(t) -> issue READ(t+1)
// un-gated -> 32 MFMA on current regs (LDS pipe overlaps MFMA pipe) ->
// lgkmcnt(0) + sched_barrier(0)  (rule 18). One barrier/iter. NT must be even.

__global__ __launch_bounds__(256) void gemm_fused(
    const u16* __restrict__ A, const u16* __restrict__ B,
    u16* __restrict__ H, const float* __restrict__ bias,
    float* __restrict__ partS, float* __restrict__ partS2,
    int M, int N, int K)
{
    __shared__ __align__(16) u16 As[2][128 * 64];
    __shared__ __align__(16) u16 Bs[2][128 * 64];

    const int tid  = threadIdx.x;
    const int wid  = tid >> 6;
    const int lane = tid & 63;
    const int lr   = lane & 15;
    const int hk   = lane >> 4;
    const int x7   = lr & 7;
    const int wr   = wid >> 1;
    const int wc   = wid & 1;

    int mm, jj;
    xcd_map(mm, jj);
    const int row0 = mm * 128;
    const int col0 = jj * 128;

    const int s_r = tid >> 3;
    const int s_c = (((tid & 7) ^ (s_r & 7)) << 3);
    const u16* gA = A + (size_t)(row0 + s_r) * K + s_c;
    const u16* gB = B + (size_t)(col0 + s_r) * K + s_c;

    int a_base[4], b_base[4];
    #pragma unroll
    for (int i = 0; i < 4; ++i) a_base[i] = (wr * 64 + i * 16 + lr) * 64;
    #pragma unroll
    for (int j = 0; j < 4; ++j) b_base[j] = (wc * 64 + j * 16 + lr) * 64;
    const int xs0 = ((hk)     ^ x7) << 3;
    const int xs1 = ((hk + 4) ^ x7) << 3;

    f32x4 acc[4][4];
    #pragma unroll
    for (int i = 0; i < 4; ++i)
        #pragma unroll
        for (int j = 0; j < 4; ++j)
            acc[i][j] = (f32x4){0.f, 0.f, 0.f, 0.f};

    const int NT = K >> 6;

    auto STAGE = [&](int buf, int t) {
        const u16* pa = gA + (size_t)t * 64;
        const u16* pb = gB + (size_t)t * 64;
        #pragma unroll
        for (int i = 0; i < 4; ++i)
            async_copy16(pa + (size_t)i * 32 * K, &As[buf][i * 2048 + wid * 512]);
        #pragma unroll
        for (int i = 0; i < 4; ++i)
            async_copy16(pb + (size_t)i * 32 * K, &Bs[buf][i * 2048 + wid * 512]);
    };

    // two named fragment sets (rule #20: static indexing only)
    bf16x8 pa[4][2], pb[4][2];
    bf16x8 qa[4][2], qb[4][2];

#define READ_P(buf)                                                   \
    _Pragma("unroll")                                                 \
    for (int i = 0; i < 4; ++i) {                                     \
        pa[i][0] = *(const bf16x8*)&As[buf][a_base[i] + xs0];         \
        pa[i][1] = *(const bf16x8*)&As[buf][a_base[i] + xs1];         \
        pb[i][0] = *(const bf16x8*)&Bs[buf][b_base[i] + xs0];         \
        pb[i][1] = *(const bf16x8*)&Bs[buf][b_base[i] + xs1];         \
    }
#define READ_Q(buf)                                                   \
    _Pragma("unroll")                                                 \
    for (int i = 0; i < 4; ++i) {                                     \
        qa[i][0] = *(const bf16x8*)&As[buf][a_base[i] + xs0];         \
        qa[i][1] = *(const bf16x8*)&As[buf][a_base[i] + xs1];         \
        qb[i][0] = *(const bf16x8*)&Bs[buf][b_base[i] + xs0];         \
        qb[i][1] = *(const bf16x8*)&Bs[buf][b_base[i] + xs1];         \
    }
#define MFMA_SET(SA, SB)                                                             \
    __builtin_amdgcn_s_setprio(1);                                                   \
    _Pragma("unroll")                                                                \
    for (int kk = 0; kk < 2; ++kk)                                                   \
        _Pragma("unroll")                                                            \
        for (int i = 0; i < 4; ++i)                                                  \
            _Pragma("unroll")                                                        \
            for (int j = 0; j < 4; ++j)                                              \
                acc[i][j] = __builtin_amdgcn_mfma_f32_16x16x32_bf16(                 \
                    SA[i][kk], SB[j][kk], acc[i][j], 0, 0, 0);                       \
    __builtin_amdgcn_s_setprio(0);

    // prologue: tiles 0,1 staged; frags(0) -> P
    STAGE(0, 0);
    STAGE(1, 1);
    asm volatile("s_waitcnt vmcnt(8)" ::: "memory");   // t0 landed (own); t1 in flight
    __builtin_amdgcn_s_barrier();                      // all waves: t0 landed
    READ_P(0)
    asm volatile("s_waitcnt lgkmcnt(0)" ::: "memory");
    __builtin_amdgcn_sched_barrier(0);

#define G_ITER(T, SA, SB, READ_N)                                             \
    {                                                                         \
        asm volatile("s_waitcnt vmcnt(0)" ::: "memory");  /* own t+1 loads */ \
        __builtin_amdgcn_s_barrier();   /* all t+1 landed; buf(t) reads done */\
        if ((T) + 2 < NT) STAGE((T) & 1, (T) + 2);                            \
        if ((T) + 1 < NT) READ_N(((T) + 1) & 1)                               \
        MFMA_SET(SA, SB)                                                      \
        if ((T) + 1 < NT) {                                                   \
            asm volatile("s_waitcnt lgkmcnt(0)" ::: "memory");                \
            __builtin_amdgcn_sched_barrier(0);                                \
        }                                                                     \
    }

    for (int t2 = 0; t2 < NT; t2 += 2) {
        G_ITER(t2,     pa, pb, READ_Q)   // MFMA P = frags(t2); read frags(t2+1)->Q
        G_ITER(t2 + 1, qa, qb, READ_P)   // MFMA Q;             read frags(t2+2)->P
    }
#undef G_ITER
#undef MFMA_SET
#undef READ_P
#undef READ_Q

    // epilogue: D[row=hk*4+reg][col=lr]; (+bias), relu, bf16 store, column stats
    const int er = hk * 4;
    #pragma unroll
    for (int j = 0; j < 4; ++j) {
        const int c = col0 + wc * 64 + j * 16 + lr;
        const float bj = bias ? bias[c] : 0.f;
        float s = 0.f, s2 = 0.f;
        #pragma unroll
        for (int i = 0; i < 4; ++i) {
            const int r = row0 + wr * 64 + i * 16 + er;
            #pragma unroll
            for (int b2 = 0; b2 < 4; ++b2) {
                float x = acc[i][j][b2] + bj;
                x = x > 0.f ? x : 0.f;
                s += x; s2 += x * x;
                H[(size_t)(r + b2) * N + c] = f2bf(x);
            }
        }
        s  += __shfl_xor(s, 16, 64);  s  += __shfl_xor(s, 32, 64);
        s2 += __shfl_xor(s2, 16, 64); s2 += __shfl_xor(s2, 32, 64);
        if (hk == 0) {
            const int p = mm * 2 + wr;
            partS [(size_t)p * 1024 + c] = s;
            partS2[(size_t)p * 1024 + c] = s2;
        }
    }
}

// ---------------- BN finalize ----------------

__global__ __launch_bounds__(256) void bn_finalize(
    const float* __restrict__ partS, const float* __restrict__ partS2,
    const float* __restrict__ gamma, const float* __restrict__ beta,
    float* __restrict__ ss)
{
    int c = blockIdx.x * 256 + threadIdx.x;
    float s = 0.f, s2 = 0.f;
    #pragma unroll 8
    for (int i = 0; i < 128; ++i) {
        s  += partS [(size_t)i * 1024 + c];
        s2 += partS2[(size_t)i * 1024 + c];
    }
    float mean = s * (1.0f / 8192.0f);
    float var  = fmaxf(s2 * (1.0f / 8192.0f) - mean * mean, 0.f);
    float sc   = gamma[c] * rsqrtf(var + 1e-5f);
    ss[c]        = sc;
    ss[1024 + c] = beta[c] - mean * sc;
}

// ---------------- head: out[8192,10] = BN3(H) @ W4T (K=1024) ----------------

__global__ __launch_bounds__(256) void head_kernel(
    const u16* __restrict__ H, const u16* __restrict__ W4T,
    const float* __restrict__ ss, float* __restrict__ out)
{
    const int lane = threadIdx.x & 63;
    const int wid  = threadIdx.x >> 6;
    const int r    = blockIdx.x * 4 + wid;

    float acc[10];
    #pragma unroll
    for (int c = 0; c < 10; c++) acc[c] = 0.f;

    #pragma unroll
    for (int j = 0; j < 16; ++j) {
        int k = j * 64 + lane;
        float a = fmaf(bf2f(H[(size_t)r * 1024 + k]), ss[k], ss[1024 + k]);
        ushort8 w0 = *(const ushort8*)(W4T + (size_t)k * 16);
        acc[0] += a * bf2f(w0[0]); acc[1] += a * bf2f(w0[1]);
        acc[2] += a * bf2f(w0[2]); acc[3] += a * bf2f(w0[3]);
        acc[4] += a * bf2f(w0[4]); acc[5] += a * bf2f(w0[5]);
        acc[6] += a * bf2f(w0[6]); acc[7] += a * bf2f(w0[7]);
        u16 w8 = W4T[(size_t)k * 16 + 8];
        u16 w9 = W4T[(size_t)k * 16 + 9];
        acc[8] += a * bf2f(w8);    acc[9] += a * bf2f(w9);
    }
    #pragma unroll
    for (int c = 0; c < 10; c++) {
        float s = acc[c];
        #pragma unroll
        for (int off = 32; off > 0; off >>= 1) s += __shfl_xor(s, off, 64);
        acc[c] = s;
    }
    if (lane == 0) {
        #pragma unroll
        for (int c = 0; c < 10; c++) out[(size_t)r * 10 + c] = acc[c];
    }
}

// ---------------- launch ----------------

extern "C" void kernel_launch(void* const* d_in, const int* in_sizes, int n_in,
                              void* d_out, int out_size, void* d_ws, size_t ws_size,
                              hipStream_t stream) {
    const float* x  = (const float*)d_in[0];
    const float* W1 = (const float*)d_in[1];
    const float* W2 = (const float*)d_in[2];
    const float* W3 = (const float*)d_in[3];
    const float* W4 = (const float*)d_in[4];
    const float* g1 = (const float*)d_in[5];
    const float* b1 = (const float*)d_in[6];
    const float* g2 = (const float*)d_in[7];
    const float* b2 = (const float*)d_in[8];
    const float* g3 = (const float*)d_in[9];
    const float* b3 = (const float*)d_in[10];
    float* out = (float*)d_out;

    char* ws = (char*)d_ws;
    u16*   Xb     = (u16*)  (ws + 0);           // 50,331,648 (x bf16)
    u16*   Hb0    = (u16*)  (ws + 50331648);    // 16,777,216
    u16*   Hb1    = (u16*)  (ws + 67108864);    // 16,777,216
    u16*   W1b    = (u16*)  (ws + 83886080);    //  6,291,456
    u16*   W2p    = (u16*)  (ws + 90177536);    //  2,097,152
    u16*   W3p    = (u16*)  (ws + 92274688);    //  2,097,152
    u16*   W4T    = (u16*)  (ws + 94371840);    //     32,768
    float* partS  = (float*)(ws + 94404608);    //    524,288
    float* partS2 = (float*)(ws + 94928896);    //    524,288
    float* ss     = (float*)(ws + 95453184);    //      8,192
    float* bias2  = (float*)(ws + 95461376);    //      4,096
    float* bias3  = (float*)(ws + 95465472);    //      4,096

    pre_kernel<<<13888, 256, 0, stream>>>(x, W1, W4, Xb, W1b, W4T);

    dim3 gemm_grid(64, 8);   // M/128, N/128

    // layer 1 (bf16 x, no bias)
    gemm_fused<<<gemm_grid, 256, 0, stream>>>(Xb, W1b, Hb0, nullptr, partS, partS2, 8192, 1024, 3072);
    bn_finalize<<<4, 256, 0, stream>>>(partS, partS2, g1, b1, ss);
    rescale_w<<<256, 256, 0, stream>>>(W2, ss, W2p, bias2);

    // layer 2
    gemm_fused<<<gemm_grid, 256, 0, stream>>>(Hb0, W2p, Hb1, bias2, partS, partS2, 8192, 1024, 1024);
    bn_finalize<<<4, 256, 0, stream>>>(partS, partS2, g2, b2, ss);
    rescale_w<<<256, 256, 0, stream>>>(W3, ss, W3p, bias3);

    // layer 3
    gemm_fused<<<gemm_grid, 256, 0, stream>>>(Hb1, W3p, Hb0, bias3, partS, partS2, 8192, 1024, 1024);
    bn_finalize<<<4, 256, 0, stream>>>(partS, partS2, g3, b3, ss);

    // head (BN3 applied on the fly)
    head_kernel<<<2048, 256, 0, stream>>>(Hb0, W4T, ss, out);
}

// Round 13
// 188.835 us; speedup vs baseline: 1.4201x; 1.4201x over previous
//
#include <hip/hip_runtime.h>
#include <stdint.h>

typedef unsigned short u16;
typedef __attribute__((ext_vector_type(8))) unsigned short ushort8;
typedef __attribute__((ext_vector_type(4))) unsigned short ushort4v;
typedef __attribute__((ext_vector_type(8))) __bf16 bf16x8;
typedef __attribute__((ext_vector_type(4))) float f32x4;

__device__ __forceinline__ u16 f2bf(float f) {
    union { float f; unsigned int u; } v; v.f = f;
    unsigned int r = v.u + 0x7FFFu + ((v.u >> 16) & 1u);   // RNE
    return (u16)(r >> 16);
}
__device__ __forceinline__ float bf2f(u16 b) {
    union { unsigned int u; float f; } v; v.u = ((unsigned int)b) << 16;
    return v.f;
}

typedef __attribute__((address_space(1))) const uint32_t* gptr_t;
typedef __attribute__((address_space(3))) uint32_t* lptr_t;
__device__ __forceinline__ void async_copy16(const void* g, void* l) {
    __builtin_amdgcn_global_load_lds((gptr_t)g, (lptr_t)l, 16, 0, 0);
}

// ---------------- merged pre-pass: x->bf16, sign(W1)->bf16, W4 -> W4T ----------------
// grid 13888: [0,12288) convert, [12288,13824) binarize W1, [13824,13888) W4T

__global__ __launch_bounds__(256) void pre_kernel(
    const float* __restrict__ x, const float* __restrict__ W1,
    const float* __restrict__ W4,
    u16* __restrict__ Xb, u16* __restrict__ W1b, u16* __restrict__ W4T)
{
    const int b = blockIdx.x;
    if (b < 12288) {
        int i = b * 256 + threadIdx.x;
        const float4* p = (const float4*)(x + (size_t)i * 8);
        float4 x0 = p[0], x1 = p[1];
        ushort8 o;
        o[0] = f2bf(x0.x); o[1] = f2bf(x0.y); o[2] = f2bf(x0.z); o[3] = f2bf(x0.w);
        o[4] = f2bf(x1.x); o[5] = f2bf(x1.y); o[6] = f2bf(x1.z); o[7] = f2bf(x1.w);
        *(ushort8*)(Xb + (size_t)i * 8) = o;
    } else if (b < 13824) {
        int i = (b - 12288) * 256 + threadIdx.x;
        const float4* p = (const float4*)(W1 + (size_t)i * 8);
        float4 x0 = p[0], x1 = p[1];
        ushort8 o;
        o[0] = x0.x >= 0.f ? 0x3F80 : 0xBF80;
        o[1] = x0.y >= 0.f ? 0x3F80 : 0xBF80;
        o[2] = x0.z >= 0.f ? 0x3F80 : 0xBF80;
        o[3] = x0.w >= 0.f ? 0x3F80 : 0xBF80;
        o[4] = x1.x >= 0.f ? 0x3F80 : 0xBF80;
        o[5] = x1.y >= 0.f ? 0x3F80 : 0xBF80;
        o[6] = x1.z >= 0.f ? 0x3F80 : 0xBF80;
        o[7] = x1.w >= 0.f ? 0x3F80 : 0xBF80;
        *(ushort8*)(W1b + (size_t)i * 8) = o;
    } else {
        int idx = (b - 13824) * 256 + threadIdx.x;
        int k = idx >> 4, c = idx & 15;
        u16 v = 0;
        if (c < 10) v = (W4[(size_t)c * 1024 + k] >= 0.f) ? 0x3F80 : 0xBF80;
        W4T[idx] = v;
    }
}

// W' = bf16(sign(W)*sc_k), bias_n = sum_k sign(W)*sh_k.  W [1024][1024] f32.
__global__ __launch_bounds__(256) void rescale_w(
    const float* __restrict__ W, const float* __restrict__ ss,
    u16* __restrict__ Wp, float* __restrict__ bias)
{
    const int lane = threadIdx.x & 63;
    const int wid  = threadIdx.x >> 6;
    const int r    = blockIdx.x * 4 + wid;
    float bsum = 0.f;
    #pragma unroll
    for (int k0 = 0; k0 < 1024; k0 += 256) {
        int k = k0 + lane * 4;
        float4 w  = *(const float4*)(W + (size_t)r * 1024 + k);
        float4 sc = *(const float4*)(ss + k);
        float4 sh = *(const float4*)(ss + 1024 + k);
        ushort4v o;
        o[0] = f2bf(w.x >= 0.f ? sc.x : -sc.x);
        o[1] = f2bf(w.y >= 0.f ? sc.y : -sc.y);
        o[2] = f2bf(w.z >= 0.f ? sc.z : -sc.z);
        o[3] = f2bf(w.w >= 0.f ? sc.w : -sc.w);
        bsum += (w.x >= 0.f ? sh.x : -sh.x) + (w.y >= 0.f ? sh.y : -sh.y)
              + (w.z >= 0.f ? sh.z : -sh.z) + (w.w >= 0.f ? sh.w : -sh.w);
        *(ushort4v*)(Wp + (size_t)r * 1024 + k) = o;
    }
    #pragma unroll
    for (int off = 32; off; off >>= 1) bsum += __shfl_xor(bsum, off, 64);
    if (lane == 0) bias[r] = bsum;
}

// XCD-aware bijective swizzle for grid (64,8): the 8 col-blocks sharing an
// A-panel get ids congruent mod 8 -> same XCD L2.
__device__ __forceinline__ void xcd_map(int& mm, int& jj) {
    const int d = blockIdx.x + blockIdx.y * gridDim.x;
    mm = (d & 7) + (d >> 6) * 8;
    jj = (d >> 3) & 7;
}

// ---------------- GEMM (bf16, 16x16x32 MFMA): H = bf16(relu(A @ B^T [+ bias])), fused BN stats --
// Measured-best variant (r6/r11): 128x128 tile, BK=64, 4 waves (64x64), dbuf LDS via
// global_load_lds (linear dest, pre-swizzled global source), counted vmcnt
// (2 tiles in flight), XOR-swizzle on LDS reads. 88 VGPR -> 2 blocks/CU.

__global__ __launch_bounds__(256) void gemm_fused(
    const u16* __restrict__ A, const u16* __restrict__ B,
    u16* __restrict__ H, const float* __restrict__ bias,
    float* __restrict__ partS, float* __restrict__ partS2,
    int M, int N, int K)
{
    __shared__ __align__(16) u16 As[2][128 * 64];
    __shared__ __align__(16) u16 Bs[2][128 * 64];

    const int tid  = threadIdx.x;
    const int wid  = tid >> 6;
    const int lane = tid & 63;
    const int lr   = lane & 15;
    const int hk   = lane >> 4;
    const int x7   = lr & 7;
    const int wr   = wid >> 1;
    const int wc   = wid & 1;

    int mm, jj;
    xcd_map(mm, jj);
    const int row0 = mm * 128;
    const int col0 = jj * 128;

    const int s_r = tid >> 3;
    const int s_c = (((tid & 7) ^ (s_r & 7)) << 3);
    const u16* gA = A + (size_t)(row0 + s_r) * K + s_c;
    const u16* gB = B + (size_t)(col0 + s_r) * K + s_c;

    int a_base[4], b_base[4];
    #pragma unroll
    for (int i = 0; i < 4; ++i) a_base[i] = (wr * 64 + i * 16 + lr) * 64;
    #pragma unroll
    for (int j = 0; j < 4; ++j) b_base[j] = (wc * 64 + j * 16 + lr) * 64;
    const int xs0 = ((hk)     ^ x7) << 3;
    const int xs1 = ((hk + 4) ^ x7) << 3;

    f32x4 acc[4][4];
    #pragma unroll
    for (int i = 0; i < 4; ++i)
        #pragma unroll
        for (int j = 0; j < 4; ++j)
            acc[i][j] = (f32x4){0.f, 0.f, 0.f, 0.f};

    const int NT = K >> 6;

    auto STAGE = [&](int buf, int t) {
        const u16* pa = gA + (size_t)t * 64;
        const u16* pb = gB + (size_t)t * 64;
        #pragma unroll
        for (int i = 0; i < 4; ++i)
            async_copy16(pa + (size_t)i * 32 * K, &As[buf][i * 2048 + wid * 512]);
        #pragma unroll
        for (int i = 0; i < 4; ++i)
            async_copy16(pb + (size_t)i * 32 * K, &Bs[buf][i * 2048 + wid * 512]);
    };

    STAGE(0, 0);
    STAGE(1, 1);

    for (int t = 0; t < NT; ++t) {
        const int buf = t & 1;
        if (t + 1 < NT) asm volatile("s_waitcnt vmcnt(8)" ::: "memory");
        else            asm volatile("s_waitcnt vmcnt(0)" ::: "memory");
        __builtin_amdgcn_s_barrier();

        bf16x8 af[4][2], bg[4][2];
        #pragma unroll
        for (int i = 0; i < 4; ++i) {
            af[i][0] = *(const bf16x8*)&As[buf][a_base[i] + xs0];
            af[i][1] = *(const bf16x8*)&As[buf][a_base[i] + xs1];
        }
        #pragma unroll
        for (int j = 0; j < 4; ++j) {
            bg[j][0] = *(const bf16x8*)&Bs[buf][b_base[j] + xs0];
            bg[j][1] = *(const bf16x8*)&Bs[buf][b_base[j] + xs1];
        }
        asm volatile("s_waitcnt lgkmcnt(0)" ::: "memory");
        __builtin_amdgcn_sched_barrier(0);
        __builtin_amdgcn_s_barrier();

        if (t + 2 < NT) STAGE(buf, t + 2);

        __builtin_amdgcn_s_setprio(1);
        #pragma unroll
        for (int kk = 0; kk < 2; ++kk)
            #pragma unroll
            for (int i = 0; i < 4; ++i)
                #pragma unroll
                for (int j = 0; j < 4; ++j)
                    acc[i][j] = __builtin_amdgcn_mfma_f32_16x16x32_bf16(
                        af[i][kk], bg[j][kk], acc[i][j], 0, 0, 0);
        __builtin_amdgcn_s_setprio(0);
    }

    // epilogue: D[row=hk*4+reg][col=lr]; (+bias), relu, bf16 store, column stats
    const int er = hk * 4;
    #pragma unroll
    for (int j = 0; j < 4; ++j) {
        const int c = col0 + wc * 64 + j * 16 + lr;
        const float bj = bias ? bias[c] : 0.f;
        float s = 0.f, s2 = 0.f;
        #pragma unroll
        for (int i = 0; i < 4; ++i) {
            const int r = row0 + wr * 64 + i * 16 + er;
            #pragma unroll
            for (int b2 = 0; b2 < 4; ++b2) {
                float x = acc[i][j][b2] + bj;
                x = x > 0.f ? x : 0.f;
                s += x; s2 += x * x;
                H[(size_t)(r + b2) * N + c] = f2bf(x);
            }
        }
        s  += __shfl_xor(s, 16, 64);  s  += __shfl_xor(s, 32, 64);
        s2 += __shfl_xor(s2, 16, 64); s2 += __shfl_xor(s2, 32, 64);
        if (hk == 0) {
            const int p = mm * 2 + wr;
            partS [(size_t)p * 1024 + c] = s;
            partS2[(size_t)p * 1024 + c] = s2;
        }
    }
}

// ---------------- BN finalize ----------------

__global__ __launch_bounds__(256) void bn_finalize(
    const float* __restrict__ partS, const float* __restrict__ partS2,
    const float* __restrict__ gamma, const float* __restrict__ beta,
    float* __restrict__ ss)
{
    int c = blockIdx.x * 256 + threadIdx.x;
    float s = 0.f, s2 = 0.f;
    #pragma unroll 8
    for (int i = 0; i < 128; ++i) {
        s  += partS [(size_t)i * 1024 + c];
        s2 += partS2[(size_t)i * 1024 + c];
    }
    float mean = s * (1.0f / 8192.0f);
    float var  = fmaxf(s2 * (1.0f / 8192.0f) - mean * mean, 0.f);
    float sc   = gamma[c] * rsqrtf(var + 1e-5f);
    ss[c]        = sc;
    ss[1024 + c] = beta[c] - mean * sc;
}

// ---------------- head: out[8192,10] = BN3(H) @ W4T (K=1024) ----------------

__global__ __launch_bounds__(256) void head_kernel(
    const u16* __restrict__ H, const u16* __restrict__ W4T,
    const float* __restrict__ ss, float* __restrict__ out)
{
    const int lane = threadIdx.x & 63;
    const int wid  = threadIdx.x >> 6;
    const int r    = blockIdx.x * 4 + wid;

    float acc[10];
    #pragma unroll
    for (int c = 0; c < 10; c++) acc[c] = 0.f;

    #pragma unroll
    for (int j = 0; j < 16; ++j) {
        int k = j * 64 + lane;
        float a = fmaf(bf2f(H[(size_t)r * 1024 + k]), ss[k], ss[1024 + k]);
        ushort8 w0 = *(const ushort8*)(W4T + (size_t)k * 16);
        acc[0] += a * bf2f(w0[0]); acc[1] += a * bf2f(w0[1]);
        acc[2] += a * bf2f(w0[2]); acc[3] += a * bf2f(w0[3]);
        acc[4] += a * bf2f(w0[4]); acc[5] += a * bf2f(w0[5]);
        acc[6] += a * bf2f(w0[6]); acc[7] += a * bf2f(w0[7]);
        u16 w8 = W4T[(size_t)k * 16 + 8];
        u16 w9 = W4T[(size_t)k * 16 + 9];
        acc[8] += a * bf2f(w8);    acc[9] += a * bf2f(w9);
    }
    #pragma unroll
    for (int c = 0; c < 10; c++) {
        float s = acc[c];
        #pragma unroll
        for (int off = 32; off > 0; off >>= 1) s += __shfl_xor(s, off, 64);
        acc[c] = s;
    }
    if (lane == 0) {
        #pragma unroll
        for (int c = 0; c < 10; c++) out[(size_t)r * 10 + c] = acc[c];
    }
}

// ---------------- launch ----------------

extern "C" void kernel_launch(void* const* d_in, const int* in_sizes, int n_in,
                              void* d_out, int out_size, void* d_ws, size_t ws_size,
                              hipStream_t stream) {
    const float* x  = (const float*)d_in[0];
    const float* W1 = (const float*)d_in[1];
    const float* W2 = (const float*)d_in[2];
    const float* W3 = (const float*)d_in[3];
    const float* W4 = (const float*)d_in[4];
    const float* g1 = (const float*)d_in[5];
    const float* b1 = (const float*)d_in[6];
    const float* g2 = (const float*)d_in[7];
    const float* b2 = (const float*)d_in[8];
    const float* g3 = (const float*)d_in[9];
    const float* b3 = (const float*)d_in[10];
    float* out = (float*)d_out;

    char* ws = (char*)d_ws;
    u16*   Xb     = (u16*)  (ws + 0);           // 50,331,648 (x bf16)
    u16*   Hb0    = (u16*)  (ws + 50331648);    // 16,777,216
    u16*   Hb1    = (u16*)  (ws + 67108864);    // 16,777,216
    u16*   W1b    = (u16*)  (ws + 83886080);    //  6,291,456
    u16*   W2p    = (u16*)  (ws + 90177536);    //  2,097,152
    u16*   W3p    = (u16*)  (ws + 92274688);    //  2,097,152
    u16*   W4T    = (u16*)  (ws + 94371840);    //     32,768
    float* partS  = (float*)(ws + 94404608);    //    524,288
    float* partS2 = (float*)(ws + 94928896);    //    524,288
    float* ss     = (float*)(ws + 95453184);    //      8,192
    float* bias2  = (float*)(ws + 95461376);    //      4,096
    float* bias3  = (float*)(ws + 95465472);    //      4,096

    pre_kernel<<<13888, 256, 0, stream>>>(x, W1, W4, Xb, W1b, W4T);

    dim3 gemm_grid(64, 8);   // M/128, N/128

    // layer 1 (bf16 x, no bias)
    gemm_fused<<<gemm_grid, 256, 0, stream>>>(Xb, W1b, Hb0, nullptr, partS, partS2, 8192, 1024, 3072);
    bn_finalize<<<4, 256, 0, stream>>>(partS, partS2, g1, b1, ss);
    rescale_w<<<256, 256, 0, stream>>>(W2, ss, W2p, bias2);

    // layer 2
    gemm_fused<<<gemm_grid, 256, 0, stream>>>(Hb0, W2p, Hb1, bias2, partS, partS2, 8192, 1024, 1024);
    bn_finalize<<<4, 256, 0, stream>>>(partS, partS2, g2, b2, ss);
    rescale_w<<<256, 256, 0, stream>>>(W3, ss, W3p, bias3);

    // layer 3
    gemm_fused<<<gemm_grid, 256, 0, stream>>>(Hb1, W3p, Hb0, bias3, partS, partS2, 8192, 1024, 1024);
    bn_finalize<<<4, 256, 0, stream>>>(partS, partS2, g3, b3, ss);

    // head (BN3 applied on the fly)
    head_kernel<<<2048, 256, 0, stream>>>(Hb0, W4T, ss, out);
}